// Round 10
// baseline (543.838 us; speedup 1.0000x reference)
//
#include <hip/hip_runtime.h>
#include <hip/hip_bf16.h>
#include <stdint.h>
#include <type_traits>

// Problem constants (S=2048, B=4, H=1024, F=4096, E=8)
#define SB   8192
#define HDIM 1024
#define FDIM 4096
#define EDIM 8

typedef __bf16 bf16x8 __attribute__((ext_vector_type(8)));
typedef float  f32x4  __attribute__((ext_vector_type(4)));

__device__ __forceinline__ void g2l16(const void* g, void* l) {
  __builtin_amdgcn_global_load_lds(
      (const __attribute__((address_space(1))) uint32_t*)g,
      (__attribute__((address_space(3))) uint32_t*)l, 16, 0, 0);
}

__device__ __forceinline__ unsigned short f2bf(float f) {
  __hip_bfloat16 b = __float2bfloat16(f);
  return *reinterpret_cast<unsigned short*>(&b);
}

// inline-asm ds_read_b128 with compile-time offset immediate.
template <int IMM>
__device__ __forceinline__ bf16x8 lds_rd128(int addr) {
  static_assert(IMM >= 0 && IMM < 65536, "ds offset");
  bf16x8 r;
  asm volatile("ds_read_b128 %0, %1 offset:%2" : "=v"(r) : "v"(addr), "n"(IMM));
  return r;
}

// ---------------- prep: cast X + gw1 to bf16, zero colsum (grid-stride) ----
__global__ void prep_kernel(const float4* __restrict__ X,
                            ushort4* __restrict__ Xbf,
                            const float4* __restrict__ gw1,
                            ushort4* __restrict__ gw1bf,
                            float* __restrict__ colsum) {
  constexpr int n4x = SB * HDIM / 4;
  constexpr int n4g = HDIM * HDIM / 4;
  constexpr int total = n4x + n4g;
  const int tid0 = blockIdx.x * blockDim.x + threadIdx.x;
  const int stride = gridDim.x * blockDim.x;
  if (tid0 < HDIM) colsum[tid0] = 0.f;
  for (int i = tid0; i < total; i += stride) {
    const bool fx = i < n4x;
    const int j = fx ? i : i - n4x;
    const float4 v = fx ? X[j] : gw1[j];
    ushort4 o;
    o.x = f2bf(v.x); o.y = f2bf(v.y); o.z = f2bf(v.z); o.w = f2bf(v.w);
    if (fx) Xbf[j] = o; else gw1bf[j] = o;
  }
}

// ---------------- lambda: one block per expert, wave-shuffle reduce --------
__global__ void lam_kernel(const float* __restrict__ colsum,
                           const float* __restrict__ gw2,
                           const float* __restrict__ gb2,
                           float* __restrict__ lam) {
  const int e = blockIdx.x;
  const int tid = threadIdx.x;
  __shared__ float red[4];
  float p = 0.f;
  for (int h = tid; h < HDIM; h += 256) p += colsum[h] * gw2[e * HDIM + h];
#pragma unroll
  for (int off = 32; off > 0; off >>= 1) p += __shfl_down(p, off);
  if ((tid & 63) == 0) red[tid >> 6] = p;
  __syncthreads();
  if (tid == 0)
    lam[e] = gb2[e] + (red[0] + red[1] + red[2] + red[3]) * (1.f / 8192.f);
}

// ---------------- merge_all v2: explicit-ILP streaming merge ---------------
// R9 diagnosis: v1 ran at 1.5 TB/s HBM with VGPR_Count=32 -- the register
// allocator minimized regs, so the 9 independent loads per iteration could
// not stay concurrently in flight (latency-bound, VALUBusy 2.4%).  v2 gives
// each thread exactly 2 j-indices per weight half (sizes are exact:
// 2*n4 == 4 * 2048*256) and loads 18 float4 into named registers before
// accumulating -> ~18KB outstanding per wave.  GRID MUST BE 2048x256.
__global__ void __launch_bounds__(256)
merge_all(const float4* __restrict__ bw1, const float4* __restrict__ tw1,
          ushort4* __restrict__ w1m,
          const float4* __restrict__ bw2, const float4* __restrict__ tw2,
          ushort4* __restrict__ w2m,
          const float* __restrict__ bb1, const float* __restrict__ tb1,
          float* __restrict__ b1m,
          const float* __restrict__ bb2, const float* __restrict__ tb2,
          float* __restrict__ b2m,
          const float* __restrict__ lam) {
  constexpr int n4 = FDIM * HDIM / 4;       // 1,048,576
  constexpr int STR = 2048 * 256;           // grid threads
  static_assert(2 * STR == n4, "grid/problem size mismatch");
  float l[EDIM];
#pragma unroll
  for (int e = 0; e < EDIM; ++e) l[e] = lam[e];
  const int t0 = blockIdx.x * 256 + threadIdx.x;
  // biases (grid is large enough)
  if (t0 < FDIM) {
    float v = bb1[t0];
#pragma unroll
    for (int e = 0; e < EDIM; ++e) v += l[e] * tb1[e * FDIM + t0];
    b1m[t0] = v;
  } else if (t0 < FDIM + HDIM) {
    const int j = t0 - FDIM;
    float v = bb2[j];
#pragma unroll
    for (int e = 0; e < EDIM; ++e) v += l[e] * tb2[e * HDIM + j];
    b2m[j] = v;
  }
  // weights: each half processed with 2-deep explicit ILP (18 loads live)
  auto half = [&](const float4* __restrict__ bp, const float4* __restrict__ tp,
                  ushort4* __restrict__ op) {
    const int j0 = t0, j1 = t0 + STR;
    float4 v0 = bp[j0];
    float4 v1 = bp[j1];
    float4 ta[EDIM], tb[EDIM];
#pragma unroll
    for (int e = 0; e < EDIM; ++e) {
      ta[e] = tp[(size_t)e * n4 + j0];
      tb[e] = tp[(size_t)e * n4 + j1];
    }
#pragma unroll
    for (int e = 0; e < EDIM; ++e) {
      v0.x += l[e] * ta[e].x; v0.y += l[e] * ta[e].y;
      v0.z += l[e] * ta[e].z; v0.w += l[e] * ta[e].w;
      v1.x += l[e] * tb[e].x; v1.y += l[e] * tb[e].y;
      v1.z += l[e] * tb[e].z; v1.w += l[e] * tb[e].w;
    }
    ushort4 o0, o1;
    o0.x = f2bf(v0.x); o0.y = f2bf(v0.y); o0.z = f2bf(v0.z); o0.w = f2bf(v0.w);
    o1.x = f2bf(v1.x); o1.y = f2bf(v1.y); o1.z = f2bf(v1.z); o1.w = f2bf(v1.w);
    op[j0] = o0;
    op[j1] = o1;
  };
  half(bw1, tw1, w1m);
  half(bw2, tw2, w2m);
}

// ---------------------------------------------------------------------------
// gemm2p: ring-buffer pipelined MFMA bt-GEMM.  C[M,N] = A[M,K]*B[N,K]^T
// R8 verdict (kept frozen): every geometry in this 1-barrier-per-BK family
// lands at ~810 TF (scheduling-invariant) -- structural ceiling.  Config:
// 64x64 wave tiles,
//   * 512-thr (WR4xWC2) 256x128 tile, RING=3 (72KB, 2 blocks/CU) - GEMM6.
//   * 256-thr (WR2xWC2) 128x128 tile, RING=4 (64KB, 2 blocks/CU) - gate,G7.
// BK=32; iter j stages tile j+RING-1 into the slot read at iter j-1 (drained
// by lgkmcnt(0)+barrier there); confirm of tile j+1 waits vmcnt(ahead*LPI)
// counted, never 0 until the tail.  Swizzled content via pre-swizzled global
// source + lane-linear LDS dest (rule 21); asm ds_read imm offsets.
// MODE 0: bias+relu colsum atomicAdd.  1: bias+relu bf16.  2: bias fp32.
template <int MODE, int BM, int BN, int WR, int WC, int RING>
__global__ void __launch_bounds__(WR * WC * 64, 4)
gemm2p(const ushort* __restrict__ A, const ushort* __restrict__ B,
       const float* __restrict__ bias, void* __restrict__ Cout,
       int M, int N, int K) {
  constexpr int THREADS = WR * WC * 64;
  constexpr int MI = (BM / WR) / 16;
  constexpr int NI = (BN / WC) / 16;
  static_assert(MI == 4 && NI == 4, "64x64 wave tile expected");
  constexpr int RPU = THREADS / 4;        // rows per g2l16 unit
  constexpr int UA  = BM / RPU;           // A units per tile
  constexpr int UB  = BN / RPU;           // B units per tile
  constexpr int LPI = UA + UB;            // loads per tile
  constexpr int AR_E = BM * 32;           // A slot elems
  constexpr int BR_E = BN * 32;           // B slot elems
  constexpr int ASB  = BM * 64;           // A slot bytes
  constexpr int BSB  = BN * 64;           // B slot bytes
  extern __shared__ __align__(16) ushort smem[];
  (void)M;

  const int tid  = threadIdx.x;
  const int lane = tid & 63;
  const int wave = tid >> 6;
  const int wm = wave / WC, wn = wave % WC;
  const int lr = lane & 15, lq = lane >> 4;

  // XCD-aware swizzle (gridDim.y % 8 == 0)
  const int bid = blockIdx.y * gridDim.x + blockIdx.x;
  const int gx  = gridDim.x;
  const int Yc  = gridDim.y >> 3;
  const int xcd = bid & 7;
  const int tt  = bid >> 3;
  const int tq  = tt / gx;
  const int ty  = xcd * Yc + tq;
  const int tx  = tt - tq * gx;
  const int m0 = ty * BM, n0 = tx * BN;

  const int NT = K >> 5;  // BK=32 steps

  // ---- LDS read bases (swizzle term lane-constant: row steps of 16)
  const uint32_t smemBase =
      (uint32_t)(uintptr_t)(__attribute__((address_space(3))) ushort*)smem;
  const int rowAl = wm * (BM / WR) + lr;
  const int vA = (int)smemBase + rowAl * 64 + ((lq ^ ((rowAl >> 1) & 3)) << 4);
  const int rowBl = wn * (BN / WC) + lr;
  const int vB = (int)smemBase + RING * ASB + rowBl * 64 +
                 ((lq ^ ((rowBl >> 1) & 3)) << 4);

  // ---- staging pointers (global src pre-swizzled, LDS dest lane-linear).
  const int rr = tid >> 2;
  const int colS = ((tid & 3) ^ ((rr >> 1) & 3)) * 8;
  const ushort* gAp = A + (size_t)(m0 + rr) * K + colS;
  const ushort* gBp = B + (size_t)(n0 + rr) * K + colS;
  ushort* lds0 = smem + tid * 8;

  f32x4 acc[4][4];
#pragma unroll
  for (int i = 0; i < 4; ++i)
#pragma unroll
    for (int n = 0; n < 4; ++n)
#pragma unroll
      for (int r = 0; r < 4; ++r) acc[i][n][r] = 0.f;

  // stage one K-step tile into ring slot
  auto stage = [&](int slot, int kt) {
    const int kk = kt * 32;
#pragma unroll
    for (int u = 0; u < UA; ++u)
      g2l16(gAp + (size_t)u * RPU * K + kk, lds0 + slot * AR_E + u * RPU * 32);
#pragma unroll
    for (int u = 0; u < UB; ++u)
      g2l16(gBp + (size_t)u * RPU * K + kk,
            lds0 + RING * AR_E + slot * BR_E + u * RPU * 32);
  };

  // ---- prologue: tiles 0..RING-2; confirm tile 0
#pragma unroll
  for (int r = 0; r < RING - 1; ++r) stage(r, r);
  __builtin_amdgcn_sched_barrier(0);
  asm volatile("s_waitcnt vmcnt(%0)" ::"n"((RING - 2) * LPI));
  __builtin_amdgcn_s_barrier();
  __builtin_amdgcn_sched_barrier(0);

  int rdSlot = 0, stSlot = RING - 1, stTile = RING - 1;
  for (int j = 0; j < NT; ++j) {
    if (stTile < NT) stage(stSlot, stTile);
    __builtin_amdgcn_sched_barrier(0);
    // fragment reads (asm, imm offsets off runtime ring base)
    const int aB = vA + rdSlot * ASB;
    const int bB = vB + rdSlot * BSB;
    bf16x8 bfr[4], afr[4];
    bfr[0] = lds_rd128<0>(bB);
    bfr[1] = lds_rd128<1024>(bB);
    bfr[2] = lds_rd128<2048>(bB);
    bfr[3] = lds_rd128<3072>(bB);
    afr[0] = lds_rd128<0>(aB);
    afr[1] = lds_rd128<1024>(aB);
    afr[2] = lds_rd128<2048>(aB);
    afr[3] = lds_rd128<3072>(aB);
    asm volatile("s_waitcnt lgkmcnt(0)");
    __builtin_amdgcn_sched_barrier(0);
    __builtin_amdgcn_s_setprio(1);
#pragma unroll
    for (int i = 0; i < 4; ++i)
#pragma unroll
      for (int n = 0; n < 4; ++n)
        acc[i][n] = __builtin_amdgcn_mfma_f32_16x16x32_bf16(
            afr[i], bfr[n], acc[i][n], 0, 0, 0);
    __builtin_amdgcn_s_setprio(0);
    __builtin_amdgcn_sched_barrier(0);
    // confirm tile j+1 resident (counted; issued RING-2 iters earlier)
    if (j + 1 < NT) {
      const int ls = stTile < NT ? stTile : NT - 1;
      const int ahead = ls - (j + 1);
      if constexpr (RING == 3) {
        if (ahead >= 1) asm volatile("s_waitcnt vmcnt(%0)" ::"n"(LPI));
        else            asm volatile("s_waitcnt vmcnt(0)");
      } else {  // RING == 4
        if (ahead >= 2)      asm volatile("s_waitcnt vmcnt(%0)" ::"n"(2 * LPI));
        else if (ahead == 1) asm volatile("s_waitcnt vmcnt(%0)" ::"n"(LPI));
        else                 asm volatile("s_waitcnt vmcnt(0)");
      }
    }
    __builtin_amdgcn_s_barrier();
    __builtin_amdgcn_sched_barrier(0);
    rdSlot = (rdSlot + 1 == RING) ? 0 : rdSlot + 1;
    stSlot = (stSlot + 1 == RING) ? 0 : stSlot + 1;
    ++stTile;
  }

  // ---- epilogue.  C/D layout (verified m89/m91): col=ni*16+lr, row=lq*4+r.
  const int gm = m0 + wm * (BM / WR);
  const int gn = n0 + wn * (BN / WC);
  if constexpr (MODE == 0) {
    float* colsum = (float*)Cout;
#pragma unroll
    for (int ni = 0; ni < 4; ++ni) {
      const int col = gn + ni * 16 + lr;
      const float bv = bias[col];
      float p = 0.f;
#pragma unroll
      for (int mi = 0; mi < 4; ++mi)
#pragma unroll
        for (int r = 0; r < 4; ++r) {
          float v = acc[mi][ni][r] + bv;
          p += v > 0.f ? v : 0.f;
        }
      p += __shfl_xor(p, 16);
      p += __shfl_xor(p, 32);
      if (lq == 0) atomicAdd(&colsum[col], p);
    }
  } else if constexpr (MODE == 1) {
    __hip_bfloat16* C = (__hip_bfloat16*)Cout;
#pragma unroll
    for (int ni = 0; ni < 4; ++ni) {
      const int col = gn + ni * 16 + lr;
      const float bv = bias[col];
#pragma unroll
      for (int mi = 0; mi < 4; ++mi)
#pragma unroll
        for (int r = 0; r < 4; ++r) {
          const int row = gm + mi * 16 + lq * 4 + r;
          float v = acc[mi][ni][r] + bv;
          v = v > 0.f ? v : 0.f;
          C[(size_t)row * N + col] = __float2bfloat16(v);
        }
    }
  } else {
    float* C = (float*)Cout;
#pragma unroll
    for (int ni = 0; ni < 4; ++ni) {
      const int col = gn + ni * 16 + lr;
      const float bv = bias[col];
#pragma unroll
      for (int mi = 0; mi < 4; ++mi)
#pragma unroll
        for (int r = 0; r < 4; ++r) {
          const int row = gm + mi * 16 + lq * 4 + r;
          C[(size_t)row * N + col] = acc[mi][ni][r] + bv;
        }
    }
  }
}

// ---------------------------------------------------------------------------
extern "C" void kernel_launch(void* const* d_in, const int* in_sizes, int n_in,
                              void* d_out, int out_size, void* d_ws, size_t ws_size,
                              hipStream_t stream) {
  const float* X   = (const float*)d_in[0];   // [S,B,H]
  const float* gw1 = (const float*)d_in[1];   // [H,H]
  const float* gb1 = (const float*)d_in[2];   // [H]
  const float* gw2 = (const float*)d_in[3];   // [E,H]
  const float* gb2 = (const float*)d_in[4];   // [E]
  const float* bw1 = (const float*)d_in[5];   // [F,H]
  const float* bb1 = (const float*)d_in[6];   // [F]
  const float* bw2 = (const float*)d_in[7];   // [H,F]
  const float* bb2 = (const float*)d_in[8];   // [H]
  const float* tw1 = (const float*)d_in[9];   // [E,F,H]
  const float* tb1 = (const float*)d_in[10];  // [E,F]
  const float* tw2 = (const float*)d_in[11];  // [E,H,F]
  const float* tb2 = (const float*)d_in[12];  // [E,H]
  float* out = (float*)d_out;                 // [S,B,H]

  // one-time: allow >64KB dynamic LDS where needed
  static bool s_attr = false;
  if (!s_attr) {
    (void)hipFuncSetAttribute(
        reinterpret_cast<const void*>(gemm2p<0, 128, 128, 2, 2, 4>),
        hipFuncAttributeMaxDynamicSharedMemorySize, 65536);
    (void)hipFuncSetAttribute(
        reinterpret_cast<const void*>(gemm2p<2, 128, 128, 2, 2, 4>),
        hipFuncAttributeMaxDynamicSharedMemorySize, 65536);
    (void)hipFuncSetAttribute(
        reinterpret_cast<const void*>(gemm2p<1, 256, 128, 4, 2, 3>),
        hipFuncAttributeMaxDynamicSharedMemorySize, 73728);
    s_attr = true;
  }

  // workspace carve (256B aligned)
  size_t off = 0;
  auto carve = [&](size_t bytes) -> void* {
    void* p = (char*)d_ws + off;
    off += (bytes + 255) & ~(size_t)255;
    return p;
  };
  ushort* Xbf   = (ushort*)carve((size_t)SB * HDIM * 2);     // X in bf16
  ushort* gw1bf = (ushort*)carve((size_t)HDIM * HDIM * 2);   // gate w1 bf16
  ushort* w1m   = (ushort*)carve((size_t)FDIM * HDIM * 2);   // merged w1 bf16
  ushort* w2m   = (ushort*)carve((size_t)HDIM * FDIM * 2);   // merged w2 bf16
  ushort* hbuf  = (ushort*)carve((size_t)SB * FDIM * 2);     // h bf16
  float* b1m    = (float*)carve(FDIM * 4);
  float* b2m    = (float*)carve(HDIM * 4);
  float* colsum = (float*)carve(HDIM * 4);
  float* lam    = (float*)carve(EDIM * 4);

  // 1) prep: cast X + gw1 to bf16, zero colsum (grid-stride, 2048 blocks)
  prep_kernel<<<2048, 256, 0, stream>>>(
      (const float4*)X, (ushort4*)Xbf, (const float4*)gw1, (ushort4*)gw1bf,
      colsum);

  // 2) gate GEMM -> relu -> column sums (M=8192, N=1024, K=1024), 128x128/4w
  gemm2p<0, 128, 128, 2, 2, 4><<<dim3(HDIM / 128, SB / 128), 256, 65536,
                                 stream>>>(
      Xbf, gw1bf, gb1, colsum, SB, HDIM, HDIM);

  // 3) lambda (8 blocks, one per expert)
  lam_kernel<<<EDIM, 256, 0, stream>>>(colsum, gw2, gb2, lam);

  // 4) merge weights + biases in ONE dispatch (explicit-ILP v2)
  merge_all<<<2048, 256, 0, stream>>>(
      (const float4*)bw1, (const float4*)tw1, (ushort4*)w1m,
      (const float4*)bw2, (const float4*)tw2, (ushort4*)w2m,
      bb1, tb1, b1m, bb2, tb2, b2m, lam);

  // 5) h = relu(X @ w1m^T + b1m) (M=8192, N=4096, K=1024), 256x128/8w
  gemm2p<1, 256, 128, 4, 2, 3><<<dim3(FDIM / 128, SB / 256), 512, 73728,
                                 stream>>>(
      Xbf, w1m, b1m, hbuf, SB, FDIM, HDIM);

  // 6) out = h @ w2m^T + b2m (M=8192, N=1024, K=4096), 128x128/4w
  gemm2p<2, 128, 128, 2, 2, 4><<<dim3(HDIM / 128, SB / 128), 256, 65536,
                                 stream>>>(
      hbuf, w2m, b2m, out, SB, HDIM, FDIM);
}